// Round 2
// baseline (1365.739 us; speedup 1.0000x reference)
//
#include <hip/hip_runtime.h>
#include <hip/hip_bf16.h>

// UnifiedMambaBlock: B=2, L=1024, D_MODEL=2048, D_INNER=4096, N_STATE=16,
// DT_RANK=128, D_CONV=4.  ALL inputs/outputs fp32 (per reference dtypes).
// GEMMs cast fp32->bf16 during LDS staging and use bf16 MFMA (no fp32 MFMA
// on CDNA4); epilogue/bias in fp32.  bf16-level error is accepted by the
// harness threshold (floor_eps_k=8).
//
// Pipeline (all on `stream`):
//   1. build_wcat: concat w_xdt(128)|w_xb(16)|w_xc(16) -> bf16 [256,4096]
//   2. gemm: xz[2048,8192](bf16) = u @ w_in^T + b_in
//   3. conv_silu: xc[2048,4096](bf16) from xz[:, :4096]
//   4. gemm: proj[2048,256](bf16) = xc @ wcat^T
//   5. gemm: dt[2048,4096](fp32) = softplus(proj[:,:128] @ w_dt^T + b_dt)
//   6. scan: yg (bf16, in-place over xc)
//   7. gemm: out[2048,2048](fp32) = yg @ w_out^T + b_out

#define DEV __device__ __forceinline__

typedef __attribute__((ext_vector_type(8))) __bf16 bf16x8;
typedef __attribute__((ext_vector_type(4))) float f32x4;

DEV float bf2f(__hip_bfloat16 x) { return __bfloat162float(x); }
DEV __hip_bfloat16 f2bf(float x) { return __float2bfloat16(x); }
DEV __bf16 f2b(float f) {
    __hip_bfloat16 h = __float2bfloat16(f);
    return *reinterpret_cast<__bf16*>(&h);
}
DEV float softplusf(float v) { return v > 20.f ? v : log1pf(__expf(v)); }
DEV float siluf(float v) { return v / (1.f + __expf(-v)); }

DEV void storeOut(float* C, size_t off, float v) { C[off] = v; }
DEV void storeOut(__hip_bfloat16* C, size_t off, float v) { C[off] = f2bf(v); }

// load 8 consecutive elements as bf16x8 (converting if fp32 source)
DEV bf16x8 ld8(const __hip_bfloat16* p) {
    return *reinterpret_cast<const bf16x8*>(p);
}
DEV bf16x8 ld8(const float* p) {
    const float4 a = *reinterpret_cast<const float4*>(p);
    const float4 b = *reinterpret_cast<const float4*>(p + 4);
    bf16x8 r;
    r[0] = f2b(a.x); r[1] = f2b(a.y); r[2] = f2b(a.z); r[3] = f2b(a.w);
    r[4] = f2b(b.x); r[5] = f2b(b.y); r[6] = f2b(b.z); r[7] = f2b(b.w);
    return r;
}

// ---------------------------------------------------------------------------
// Generic C = A @ W^T + bias GEMM.  A:[M,K] (lda), W:[N,K] (ldw), both fp32 or
// bf16 (converted to bf16 at staging).  C:[M,N] OutT (ldc), bias fp32.
// Block tile 128x128, BK=64, 256 threads = 4 waves in 2x2, each wave 64x64 via
// 4x4 frags of mfma_f32_16x16x32_bf16.
// Requires: M%128==0 (grid.y), N%128==0 (grid.x), K%64==0, lda/ldw mult of 8.
// ---------------------------------------------------------------------------
template <int ACT, typename TA, typename TW, typename OutT>
__global__ __launch_bounds__(256) void gemm_bt(
    const TA* __restrict__ A, int lda,
    const TW* __restrict__ W, int ldw,
    const float* __restrict__ bias,
    OutT* __restrict__ C, int ldc, int K)
{
    __shared__ __align__(16) unsigned short AsU[128 * 64];
    __shared__ __align__(16) unsigned short BsU[128 * 64];

    const int t     = threadIdx.x;
    const int mBase = blockIdx.y * 128;
    const int nBase = blockIdx.x * 128;
    const int wave  = t >> 6;
    const int lane  = t & 63;
    const int wm    = (wave >> 1) * 64;   // wave's M offset in tile
    const int wn    = (wave & 1) * 64;    // wave's N offset in tile
    const int ln15  = lane & 15;
    const int quad  = lane >> 4;

    f32x4 acc[4][4];
    const f32x4 vzero = {0.f, 0.f, 0.f, 0.f};
#pragma unroll
    for (int i = 0; i < 4; ++i)
#pragma unroll
        for (int j = 0; j < 4; ++j) acc[i][j] = vzero;

    for (int k0 = 0; k0 < K; k0 += 64) {
        // global -> regs (8 elems per thread per matrix per sub-iter)
        bf16x8 va[4], vb[4];
#pragma unroll
        for (int i = 0; i < 4; ++i) {
            int idx = i * 256 + t;            // 8-elem chunk id, 1024/tile
            int r = idx >> 3;                 // row within tile
            int c = (idx & 7) << 3;           // col (elements)
            va[i] = ld8(A + (size_t)(mBase + r) * lda + k0 + c);
            vb[i] = ld8(W + (size_t)(nBase + r) * ldw + k0 + c);
        }
        __syncthreads();   // previous iteration's LDS reads done
#pragma unroll
        for (int i = 0; i < 4; ++i) {
            int idx = i * 256 + t;
            *reinterpret_cast<bf16x8*>(&AsU[idx * 8]) = va[i];
            *reinterpret_cast<bf16x8*>(&BsU[idx * 8]) = vb[i];
        }
        __syncthreads();

#pragma unroll
        for (int kk = 0; kk < 64; kk += 32) {
            const int kof = kk + quad * 8;
            bf16x8 af[4], bfr[4];
#pragma unroll
            for (int i = 0; i < 4; ++i) {
                af[i]  = *reinterpret_cast<const bf16x8*>(&AsU[(wm + i * 16 + ln15) * 64 + kof]);
                bfr[i] = *reinterpret_cast<const bf16x8*>(&BsU[(wn + i * 16 + ln15) * 64 + kof]);
            }
#pragma unroll
            for (int i = 0; i < 4; ++i)
#pragma unroll
                for (int j = 0; j < 4; ++j)
                    acc[i][j] = __builtin_amdgcn_mfma_f32_16x16x32_bf16(af[i], bfr[j], acc[i][j], 0, 0, 0);
        }
    }

    // epilogue: C/D layout col = lane&15, row = quad*4 + reg
#pragma unroll
    for (int i = 0; i < 4; ++i) {
        const int gm = mBase + wm + i * 16 + quad * 4;
#pragma unroll
        for (int j = 0; j < 4; ++j) {
            const int gn = nBase + wn + j * 16 + ln15;
            const float bv = bias ? bias[gn] : 0.f;
#pragma unroll
            for (int r = 0; r < 4; ++r) {
                float v = acc[i][j][r] + bv;
                if (ACT == 1) v = softplusf(v);
                storeOut(C, (size_t)(gm + r) * ldc + gn, v);
            }
        }
    }
}

// ---------------------------------------------------------------------------
// wcat bf16 [256,4096]: rows 0..127 = w_xdt, 128..143 = w_xb, 144..159 = w_xc,
// rest zero.  Sources fp32.
// ---------------------------------------------------------------------------
__global__ __launch_bounds__(256) void build_wcat(
    const float* __restrict__ w_xdt,
    const float* __restrict__ w_xb,
    const float* __restrict__ w_xc,
    __hip_bfloat16* __restrict__ wcat)
{
    int tid = blockIdx.x * 256 + threadIdx.x;   // 256*4096 total
    int r = tid >> 12;
    int c = tid & 4095;
    float v = 0.f;
    if (r < 128)      v = w_xdt[r * 4096 + c];
    else if (r < 144) v = w_xb[(r - 128) * 4096 + c];
    else if (r < 160) v = w_xc[(r - 144) * 4096 + c];
    wcat[tid] = f2bf(v);
}

// ---------------------------------------------------------------------------
// causal depthwise conv (win 4, left pad 3) + bias + silu over xz[:, :4096]
// ---------------------------------------------------------------------------
__global__ __launch_bounds__(256) void conv_silu(
    const __hip_bfloat16* __restrict__ xz,   // [2048, 8192] bf16
    const float* __restrict__ conv_w,        // [4096, 4] fp32
    const float* __restrict__ conv_b,        // [4096] fp32
    __hip_bfloat16* __restrict__ xc)         // [2048, 4096] bf16
{
    int tid = blockIdx.x * 256 + threadIdx.x;  // 2048*4096 total
    int d   = tid & 4095;
    int row = tid >> 12;          // b*1024 + l
    int l   = row & 1023;
    float acc = conv_b[d];
#pragma unroll
    for (int k = 0; k < 4; ++k) {
        int ll = l - 3 + k;
        if (ll >= 0)
            acc += bf2f(xz[(size_t)(row - 3 + k) * 8192 + d]) * conv_w[d * 4 + k];
    }
    xc[tid] = f2bf(siluf(acc));
}

// ---------------------------------------------------------------------------
// selective scan: 16 lanes per channel (lane = state n), 16 channels/block.
// h[n] <- h[n]*exp(dt*A[d,n]) + x*dt*B[l,n];  y = sum_n h[n]*C[l,n] + D[d]*x
// yg = y * silu(z).   yg written IN-PLACE over xc: each (row,d) slot is read
// by its owning 16-lane group (same wave) before lane n==0 overwrites it, and
// no other group ever touches that slot.
// ---------------------------------------------------------------------------
__global__ __launch_bounds__(256) void scan_kernel(
    const float* __restrict__ dt,              // [2048, 4096] fp32
    __hip_bfloat16* xcyg,                      // [2048, 4096] bf16 in/out
    const __hip_bfloat16* __restrict__ proj,   // [2048, 256]; B at 128, C at 144
    const __hip_bfloat16* __restrict__ xz,     // [2048, 8192]; z at 4096+d
    const float* __restrict__ A_log,           // [4096, 16] fp32
    const float* __restrict__ Dp,              // [4096] fp32
    int unused)
{
    const int g  = threadIdx.x >> 4;            // group in block: 0..15
    const int n  = threadIdx.x & 15;            // state index
    const int ch = blockIdx.x * 16 + g;         // 0..8191
    const int b  = ch >> 12;
    const int d  = ch & 4095;

    const float A2   = -__expf(A_log[d * 16 + n]) * 1.44269504f; // A*log2(e)
    const float Dpar = Dp[d];

    float h = 0.f;
    const size_t rowBase = (size_t)b * 1024;
    for (int l = 0; l < 1024; ++l) {
        const size_t row = rowBase + l;
        const float dtv = dt[row * 4096 + d];
        const float xv  = bf2f(xcyg[row * 4096 + d]);
        const float Bn  = bf2f(proj[row * 256 + 128 + n]);
        const float Cn  = bf2f(proj[row * 256 + 144 + n]);
        const float dA  = exp2f(dtv * A2);
        h = h * dA + xv * dtv * Bn;
        float p = h * Cn;
        p += __shfl_xor(p, 1);
        p += __shfl_xor(p, 2);
        p += __shfl_xor(p, 4);
        p += __shfl_xor(p, 8);
        if (n == 0) {
            const float y  = p + Dpar * xv;
            const float zv = bf2f(xz[row * 8192 + 4096 + d]);
            xcyg[row * 4096 + d] = f2bf(y * siluf(zv));
        }
    }
}

// ---------------------------------------------------------------------------
extern "C" void kernel_launch(void* const* d_in, const int* in_sizes, int n_in,
                              void* d_out, int out_size, void* d_ws, size_t ws_size,
                              hipStream_t stream)
{
    const float* u      = (const float*)d_in[0];
    const float* w_in   = (const float*)d_in[1];
    const float* b_in   = (const float*)d_in[2];
    const float* w_out  = (const float*)d_in[3];
    const float* b_out  = (const float*)d_in[4];
    const float* w_dt   = (const float*)d_in[5];
    const float* b_dt   = (const float*)d_in[6];
    const float* w_xdt  = (const float*)d_in[7];
    const float* w_xb   = (const float*)d_in[8];
    const float* w_xc   = (const float*)d_in[9];
    const float* conv_w = (const float*)d_in[10];
    const float* conv_b = (const float*)d_in[11];
    const float* A_log  = (const float*)d_in[12];
    const float* D_par  = (const float*)d_in[13];
    float* out = (float*)d_out;

    char* ws = (char*)d_ws;
    __hip_bfloat16* xz   = (__hip_bfloat16*)(ws);                 // 33.5 MB [2048,8192]
    __hip_bfloat16* xc   = (__hip_bfloat16*)(ws + 33554432);      // 16.8 MB [2048,4096] (yg in-place)
    __hip_bfloat16* wcat = (__hip_bfloat16*)(ws + 50331648);      //  2.1 MB [256,4096]
    __hip_bfloat16* proj = (__hip_bfloat16*)(ws + 52428800);      //  1.0 MB [2048,256]
    float*          dtb  = (float*)(ws + 53477376);               // 33.5 MB [2048,4096]
    // total 87.0 MB

    // 1. weight concat (w_xdt | w_xb | w_xc -> bf16, zero-padded to 256 rows)
    build_wcat<<<4096, 256, 0, stream>>>(w_xdt, w_xb, w_xc, wcat);

    // 2. in_proj: xz = u @ w_in^T + b_in     (M=2048, N=8192, K=2048)
    gemm_bt<0, float, float, __hip_bfloat16><<<dim3(64, 16), 256, 0, stream>>>(
        u, 2048, w_in, 2048, b_in, xz, 8192, 2048);

    // 3. conv + silu
    conv_silu<<<32768, 256, 0, stream>>>(xz, conv_w, conv_b, xc);

    // 4. proj = xc @ wcat^T                  (M=2048, N=256, K=4096)
    gemm_bt<0, __hip_bfloat16, __hip_bfloat16, __hip_bfloat16><<<dim3(2, 16), 256, 0, stream>>>(
        xc, 4096, wcat, 4096, (const float*)nullptr, proj, 256, 4096);

    // 5. dt = softplus(proj[:, :128] @ w_dt^T + b_dt)  (M=2048, N=4096, K=128)
    gemm_bt<1, __hip_bfloat16, float, float><<<dim3(32, 16), 256, 0, stream>>>(
        proj, 256, w_dt, 128, b_dt, dtb, 4096, 128);

    // 6. selective scan -> yg (in-place over xc)
    scan_kernel<<<512, 256, 0, stream>>>(dtb, xc, proj, xz, A_log, D_par, 0);

    // 7. out = yg @ w_out^T + b_out          (M=2048, N=2048, K=4096)
    gemm_bt<0, __hip_bfloat16, float, float><<<dim3(16, 16), 256, 0, stream>>>(
        xc, 4096, w_out, 4096, b_out, out, 2048, 4096);
}

// Round 3
// 853.442 us; speedup vs baseline: 1.6003x; 1.6003x over previous
//
#include <hip/hip_runtime.h>
#include <hip/hip_bf16.h>

// UnifiedMambaBlock: B=2, L=1024, D_MODEL=2048, D_INNER=4096, N_STATE=16,
// DT_RANK=128, D_CONV=4.  ALL inputs/outputs fp32 (per reference dtypes).
// GEMMs cast fp32->bf16 during LDS staging and use bf16 MFMA (no fp32 MFMA
// on CDNA4); epilogue/bias in fp32.  bf16-level error is accepted by the
// harness threshold (floor_eps_k=8).
//
// Pipeline (all on `stream`):
//   1. build_wcat: concat w_xdt(128)|w_xb(16)|w_xc(16) -> bf16 [256,4096]
//   2. gemm: xz[2048,8192](bf16) = u @ w_in^T + b_in
//   3. conv_silu: xc[2048,4096](bf16) from xz[:, :4096]
//   4. gemm: proj[2048,256](bf16) = xc @ wcat^T
//   5. gemm: dt[2048,4096](fp32) = softplus(proj[:,:128] @ w_dt^T + b_dt)
//   6. scan: yg (bf16, in-place over xc)  -- LDS-chunked, R3 rewrite
//   7. gemm: out[2048,2048](fp32) = yg @ w_out^T + b_out

#define DEV __device__ __forceinline__

typedef __attribute__((ext_vector_type(8))) __bf16 bf16x8;
typedef __attribute__((ext_vector_type(4))) float f32x4;

DEV float bf2f(__hip_bfloat16 x) { return __bfloat162float(x); }
DEV __hip_bfloat16 f2bf(float x) { return __float2bfloat16(x); }
DEV __bf16 f2b(float f) {
    __hip_bfloat16 h = __float2bfloat16(f);
    return *reinterpret_cast<__bf16*>(&h);
}
DEV float bfu2f(unsigned short u) {
    union { unsigned int i; float f; } c; c.i = ((unsigned int)u) << 16; return c.f;
}
DEV float softplusf(float v) { return v > 20.f ? v : log1pf(__expf(v)); }
DEV float siluf(float v) { return v / (1.f + __expf(-v)); }

DEV void storeOut(float* C, size_t off, float v) { C[off] = v; }
DEV void storeOut(__hip_bfloat16* C, size_t off, float v) { C[off] = f2bf(v); }

// load 8 consecutive elements as bf16x8 (converting if fp32 source)
DEV bf16x8 ld8(const __hip_bfloat16* p) {
    return *reinterpret_cast<const bf16x8*>(p);
}
DEV bf16x8 ld8(const float* p) {
    const float4 a = *reinterpret_cast<const float4*>(p);
    const float4 b = *reinterpret_cast<const float4*>(p + 4);
    bf16x8 r;
    r[0] = f2b(a.x); r[1] = f2b(a.y); r[2] = f2b(a.z); r[3] = f2b(a.w);
    r[4] = f2b(b.x); r[5] = f2b(b.y); r[6] = f2b(b.z); r[7] = f2b(b.w);
    return r;
}

// ---------------------------------------------------------------------------
// Generic C = A @ W^T + bias GEMM.  A:[M,K] (lda), W:[N,K] (ldw), both fp32 or
// bf16 (converted to bf16 at staging).  C:[M,N] OutT (ldc), bias fp32.
// Block tile 128x128, BK=64, 256 threads = 4 waves in 2x2, each wave 64x64 via
// 4x4 frags of mfma_f32_16x16x32_bf16.
// Requires: M%128==0 (grid.y), N%128==0 (grid.x), K%64==0, lda/ldw mult of 8.
// ---------------------------------------------------------------------------
template <int ACT, typename TA, typename TW, typename OutT>
__global__ __launch_bounds__(256) void gemm_bt(
    const TA* __restrict__ A, int lda,
    const TW* __restrict__ W, int ldw,
    const float* __restrict__ bias,
    OutT* __restrict__ C, int ldc, int K)
{
    __shared__ __align__(16) unsigned short AsU[128 * 64];
    __shared__ __align__(16) unsigned short BsU[128 * 64];

    const int t     = threadIdx.x;
    const int mBase = blockIdx.y * 128;
    const int nBase = blockIdx.x * 128;
    const int wave  = t >> 6;
    const int lane  = t & 63;
    const int wm    = (wave >> 1) * 64;   // wave's M offset in tile
    const int wn    = (wave & 1) * 64;    // wave's N offset in tile
    const int ln15  = lane & 15;
    const int quad  = lane >> 4;

    f32x4 acc[4][4];
    const f32x4 vzero = {0.f, 0.f, 0.f, 0.f};
#pragma unroll
    for (int i = 0; i < 4; ++i)
#pragma unroll
        for (int j = 0; j < 4; ++j) acc[i][j] = vzero;

    for (int k0 = 0; k0 < K; k0 += 64) {
        // global -> regs (8 elems per thread per matrix per sub-iter)
        bf16x8 va[4], vb[4];
#pragma unroll
        for (int i = 0; i < 4; ++i) {
            int idx = i * 256 + t;            // 8-elem chunk id, 1024/tile
            int r = idx >> 3;                 // row within tile
            int c = (idx & 7) << 3;           // col (elements)
            va[i] = ld8(A + (size_t)(mBase + r) * lda + k0 + c);
            vb[i] = ld8(W + (size_t)(nBase + r) * ldw + k0 + c);
        }
        __syncthreads();   // previous iteration's LDS reads done
#pragma unroll
        for (int i = 0; i < 4; ++i) {
            int idx = i * 256 + t;
            *reinterpret_cast<bf16x8*>(&AsU[idx * 8]) = va[i];
            *reinterpret_cast<bf16x8*>(&BsU[idx * 8]) = vb[i];
        }
        __syncthreads();

#pragma unroll
        for (int kk = 0; kk < 64; kk += 32) {
            const int kof = kk + quad * 8;
            bf16x8 af[4], bfr[4];
#pragma unroll
            for (int i = 0; i < 4; ++i) {
                af[i]  = *reinterpret_cast<const bf16x8*>(&AsU[(wm + i * 16 + ln15) * 64 + kof]);
                bfr[i] = *reinterpret_cast<const bf16x8*>(&BsU[(wn + i * 16 + ln15) * 64 + kof]);
            }
#pragma unroll
            for (int i = 0; i < 4; ++i)
#pragma unroll
                for (int j = 0; j < 4; ++j)
                    acc[i][j] = __builtin_amdgcn_mfma_f32_16x16x32_bf16(af[i], bfr[j], acc[i][j], 0, 0, 0);
        }
    }

    // epilogue: C/D layout col = lane&15, row = quad*4 + reg
#pragma unroll
    for (int i = 0; i < 4; ++i) {
        const int gm = mBase + wm + i * 16 + quad * 4;
#pragma unroll
        for (int j = 0; j < 4; ++j) {
            const int gn = nBase + wn + j * 16 + ln15;
            const float bv = bias ? bias[gn] : 0.f;
#pragma unroll
            for (int r = 0; r < 4; ++r) {
                float v = acc[i][j][r] + bv;
                if (ACT == 1) v = softplusf(v);
                storeOut(C, (size_t)(gm + r) * ldc + gn, v);
            }
        }
    }
}

// ---------------------------------------------------------------------------
// wcat bf16 [256,4096]: rows 0..127 = w_xdt, 128..143 = w_xb, 144..159 = w_xc,
// rest zero.  Sources fp32.
// ---------------------------------------------------------------------------
__global__ __launch_bounds__(256) void build_wcat(
    const float* __restrict__ w_xdt,
    const float* __restrict__ w_xb,
    const float* __restrict__ w_xc,
    __hip_bfloat16* __restrict__ wcat)
{
    int tid = blockIdx.x * 256 + threadIdx.x;   // 256*4096 total
    int r = tid >> 12;
    int c = tid & 4095;
    float v = 0.f;
    if (r < 128)      v = w_xdt[r * 4096 + c];
    else if (r < 144) v = w_xb[(r - 128) * 4096 + c];
    else if (r < 160) v = w_xc[(r - 144) * 4096 + c];
    wcat[tid] = f2bf(v);
}

// ---------------------------------------------------------------------------
// causal depthwise conv (win 4, left pad 3) + bias + silu over xz[:, :4096]
// ---------------------------------------------------------------------------
__global__ __launch_bounds__(256) void conv_silu(
    const __hip_bfloat16* __restrict__ xz,   // [2048, 8192] bf16
    const float* __restrict__ conv_w,        // [4096, 4] fp32
    const float* __restrict__ conv_b,        // [4096] fp32
    __hip_bfloat16* __restrict__ xc)         // [2048, 4096] bf16
{
    int tid = blockIdx.x * 256 + threadIdx.x;  // 2048*4096 total
    int d   = tid & 4095;
    int row = tid >> 12;          // b*1024 + l
    int l   = row & 1023;
    float acc = conv_b[d];
#pragma unroll
    for (int k = 0; k < 4; ++k) {
        int ll = l - 3 + k;
        if (ll >= 0)
            acc += bf2f(xz[(size_t)(row - 3 + k) * 8192 + d]) * conv_w[d * 4 + k];
    }
    xc[tid] = f2bf(siluf(acc));
}

// ---------------------------------------------------------------------------
// selective scan, LDS-chunked (R3).
// 16 lanes per channel (lane = state n), 16 channels per block, block = 256.
// Time is processed in chunks of T=128: cooperative coalesced global->LDS
// load of dt/x/z/B/C, then a sequential compute phase entirely out of LDS
// (the only loop-carried dep is the single h FMA chain), then a staged
// coalesced store of the gated output.  yg overwrites xc in place (chunk
// rows are staged into LDS before being overwritten; later chunks read
// strictly later rows).
// ---------------------------------------------------------------------------
#define SCAN_T 128

__global__ __launch_bounds__(256) void scan_kernel(
    const float* __restrict__ dt,              // [2048, 4096] fp32
    __hip_bfloat16* xcyg,                      // [2048, 4096] bf16 in/out
    const __hip_bfloat16* __restrict__ proj,   // [2048, 256]; B at 128, C at 144
    const __hip_bfloat16* __restrict__ xz,     // [2048, 8192]; z at 4096+d
    const float* __restrict__ A_log,           // [4096, 16] fp32
    const float* __restrict__ Dp)              // [4096] fp32
{
    __shared__ __align__(16) float          s_dt[SCAN_T * 16];  // 8 KB
    __shared__ __align__(16) unsigned short s_x [SCAN_T * 16];  // 4 KB
    __shared__ __align__(16) unsigned short s_z [SCAN_T * 16];  // 4 KB
    __shared__ __align__(16) unsigned short s_B [SCAN_T * 16];  // 4 KB
    __shared__ __align__(16) unsigned short s_C [SCAN_T * 16];  // 4 KB
    __shared__ __align__(16) unsigned short s_y [SCAN_T * 16];  // 4 KB

    const int t  = threadIdx.x;
    const int g  = t >> 4;                      // group in block: 0..15
    const int n  = t & 15;                      // state index
    const int ch0 = blockIdx.x * 16;            // first channel of block
    const int b  = ch0 >> 12;
    const int d0 = ch0 & 4095;
    const int d  = d0 + g;

    const float A2   = -__expf(A_log[d * 16 + n]) * 1.44269504f; // A*log2(e)
    const float Dpar = Dp[d];

    const size_t rowBase = (size_t)b * 1024;
    float h = 0.f;

    for (int t0 = 0; t0 < 1024; t0 += SCAN_T) {
        __syncthreads();   // previous chunk's LDS fully consumed

        // ---- load phase (coalesced, vectorized) ----
        // dt: SCAN_T x 16 fp32 -> 512 float4; thread handles 2
#pragma unroll
        for (int i = 0; i < 2; ++i) {
            int f   = i * 256 + t;
            int row = f >> 2, c4 = (f & 3) << 2;
            *reinterpret_cast<float4*>(&s_dt[row * 16 + c4]) =
                *reinterpret_cast<const float4*>(&dt[(rowBase + t0 + row) * 4096 + d0 + c4]);
        }
        // x, z: SCAN_T x 16 bf16 -> 256 uint4 each; thread handles 1 of each
        {
            int row = t >> 1, hh = (t & 1) << 3;
            *reinterpret_cast<uint4*>(&s_x[row * 16 + hh]) =
                *reinterpret_cast<const uint4*>(&xcyg[(rowBase + t0 + row) * 4096 + d0 + hh]);
            *reinterpret_cast<uint4*>(&s_z[row * 16 + hh]) =
                *reinterpret_cast<const uint4*>(&xz[(rowBase + t0 + row) * 8192 + 4096 + d0 + hh]);
        }
        // B|C: proj cols 128..159 = 32 bf16 = 4 uint4 per row; 512 total
#pragma unroll
        for (int i = 0; i < 2; ++i) {
            int q   = i * 256 + t;
            int row = q >> 2, part = q & 3;
            uint4 v = *reinterpret_cast<const uint4*>(
                &proj[(rowBase + t0 + row) * 256 + 128 + part * 8]);
            if (part < 2)
                *reinterpret_cast<uint4*>(&s_B[row * 16 + part * 8]) = v;
            else
                *reinterpret_cast<uint4*>(&s_C[row * 16 + (part - 2) * 8]) = v;
        }
        __syncthreads();

        // ---- compute phase (all operands in LDS) ----
#pragma unroll 4
        for (int l = 0; l < SCAN_T; ++l) {
            const float dtv = s_dt[l * 16 + g];
            const float xv  = bfu2f(s_x[l * 16 + g]);
            const float Bn  = bfu2f(s_B[l * 16 + n]);
            const float Cn  = bfu2f(s_C[l * 16 + n]);
            const float dA  = exp2f(dtv * A2);
            h = h * dA + xv * dtv * Bn;
            float p = h * Cn;
            p += __shfl_xor(p, 1);
            p += __shfl_xor(p, 2);
            p += __shfl_xor(p, 4);
            p += __shfl_xor(p, 8);
            if (n == 0) {
                const float zv = bfu2f(s_z[l * 16 + g]);
                __hip_bfloat16 yb = f2bf((p + Dpar * xv) * siluf(zv));
                s_y[l * 16 + g] = *reinterpret_cast<unsigned short*>(&yb);
            }
        }
        __syncthreads();

        // ---- store phase (coalesced) ----
        {
            int row = t >> 1, hh = (t & 1) << 3;
            *reinterpret_cast<uint4*>(&xcyg[(rowBase + t0 + row) * 4096 + d0 + hh]) =
                *reinterpret_cast<uint4*>(&s_y[row * 16 + hh]);
        }
    }
}

// ---------------------------------------------------------------------------
extern "C" void kernel_launch(void* const* d_in, const int* in_sizes, int n_in,
                              void* d_out, int out_size, void* d_ws, size_t ws_size,
                              hipStream_t stream)
{
    const float* u      = (const float*)d_in[0];
    const float* w_in   = (const float*)d_in[1];
    const float* b_in   = (const float*)d_in[2];
    const float* w_out  = (const float*)d_in[3];
    const float* b_out  = (const float*)d_in[4];
    const float* w_dt   = (const float*)d_in[5];
    const float* b_dt   = (const float*)d_in[6];
    const float* w_xdt  = (const float*)d_in[7];
    const float* w_xb   = (const float*)d_in[8];
    const float* w_xc   = (const float*)d_in[9];
    const float* conv_w = (const float*)d_in[10];
    const float* conv_b = (const float*)d_in[11];
    const float* A_log  = (const float*)d_in[12];
    const float* D_par  = (const float*)d_in[13];
    float* out = (float*)d_out;

    char* ws = (char*)d_ws;
    __hip_bfloat16* xz   = (__hip_bfloat16*)(ws);                 // 33.5 MB [2048,8192]
    __hip_bfloat16* xc   = (__hip_bfloat16*)(ws + 33554432);      // 16.8 MB [2048,4096] (yg in-place)
    __hip_bfloat16* wcat = (__hip_bfloat16*)(ws + 50331648);      //  2.1 MB [256,4096]
    __hip_bfloat16* proj = (__hip_bfloat16*)(ws + 52428800);      //  1.0 MB [2048,256]
    float*          dtb  = (float*)(ws + 53477376);               // 33.5 MB [2048,4096]
    // total 87.0 MB

    // 1. weight concat (w_xdt | w_xb | w_xc -> bf16, zero-padded to 256 rows)
    build_wcat<<<4096, 256, 0, stream>>>(w_xdt, w_xb, w_xc, wcat);

    // 2. in_proj: xz = u @ w_in^T + b_in     (M=2048, N=8192, K=2048)
    gemm_bt<0, float, float, __hip_bfloat16><<<dim3(64, 16), 256, 0, stream>>>(
        u, 2048, w_in, 2048, b_in, xz, 8192, 2048);

    // 3. conv + silu
    conv_silu<<<32768, 256, 0, stream>>>(xz, conv_w, conv_b, xc);

    // 4. proj = xc @ wcat^T                  (M=2048, N=256, K=4096)
    gemm_bt<0, __hip_bfloat16, __hip_bfloat16, __hip_bfloat16><<<dim3(2, 16), 256, 0, stream>>>(
        xc, 4096, wcat, 4096, (const float*)nullptr, proj, 256, 4096);

    // 5. dt = softplus(proj[:, :128] @ w_dt^T + b_dt)  (M=2048, N=4096, K=128)
    gemm_bt<1, __hip_bfloat16, float, float><<<dim3(32, 16), 256, 0, stream>>>(
        proj, 256, w_dt, 128, b_dt, dtb, 4096, 128);

    // 6. selective scan -> yg (in-place over xc)
    scan_kernel<<<512, 256, 0, stream>>>(dtb, xc, proj, xz, A_log, D_par);

    // 7. out = yg @ w_out^T + b_out          (M=2048, N=2048, K=4096)
    gemm_bt<0, __hip_bfloat16, float, float><<<dim3(16, 16), 256, 0, stream>>>(
        xc, 4096, w_out, 4096, b_out, out, 2048, 4096);
}

// Round 4
// 649.289 us; speedup vs baseline: 2.1034x; 1.3144x over previous
//
#include <hip/hip_runtime.h>
#include <hip/hip_bf16.h>

// UnifiedMambaBlock: B=2, L=1024, D_MODEL=2048, D_INNER=4096, N_STATE=16,
// DT_RANK=128, D_CONV=4.  ALL inputs/outputs fp32 (per reference dtypes).
// bf16 MFMA compute (no fp32 MFMA on CDNA4); fp32 epilogues.
//
// Pipeline:
//   0. cast u->u_bf, w_in->w_in_bf (overlapped dead ws regions)
//   1. build_wcat: concat w_xdt|w_xb|w_xc -> bf16 [256,4096]
//   2. gemm: xz[2048,8192](bf16) = u_bf @ w_in_bf^T + b_in
//   3. conv_silu: xc[2048,4096](bf16) from xz[:, :4096]   (overwrites u_bf)
//   4. gemm: proj[2048,256](bf16) = xc @ wcat^T
//   5. gemm: dt[2048,4096](fp32) = softplus(proj[:,:128] @ w_dt^T + b_dt)
//   6. scan (R4): transposed-LDS + DPP reduce + chunk prefetch; yg in-place
//   7. cast w_out->w_out_bf (dtb region, dead after scan)
//   8. gemm: out[2048,2048](fp32) = yg @ w_out_bf^T + b_out

#define DEV __device__ __forceinline__

typedef __attribute__((ext_vector_type(8))) __bf16 bf16x8;
typedef __attribute__((ext_vector_type(4))) float f32x4;

DEV float bf2f(__hip_bfloat16 x) { return __bfloat162float(x); }
DEV __hip_bfloat16 f2bf(float x) { return __float2bfloat16(x); }
DEV __bf16 f2b(float f) {
    __hip_bfloat16 h = __float2bfloat16(f);
    return *reinterpret_cast<__bf16*>(&h);
}
DEV float bfu2f(unsigned short u) {
    union { unsigned int i; float f; } c; c.i = ((unsigned int)u) << 16; return c.f;
}
DEV unsigned short f2bfu(float x) {
    __hip_bfloat16 h = __float2bfloat16(x);
    return *reinterpret_cast<unsigned short*>(&h);
}
DEV float softplusf(float v) { return v > 20.f ? v : log1pf(__expf(v)); }
DEV float siluf(float v) { return v / (1.f + __expf(-v)); }

DEV void storeOut(float* C, size_t off, float v) { C[off] = v; }
DEV void storeOut(__hip_bfloat16* C, size_t off, float v) { C[off] = f2bf(v); }

DEV bf16x8 ld8(const __hip_bfloat16* p) {
    return *reinterpret_cast<const bf16x8*>(p);
}
DEV bf16x8 ld8(const float* p) {
    const float4 a = *reinterpret_cast<const float4*>(p);
    const float4 b = *reinterpret_cast<const float4*>(p + 4);
    bf16x8 r;
    r[0] = f2b(a.x); r[1] = f2b(a.y); r[2] = f2b(a.z); r[3] = f2b(a.w);
    r[4] = f2b(b.x); r[5] = f2b(b.y); r[6] = f2b(b.z); r[7] = f2b(b.w);
    return r;
}

// DPP-based add of lane (permuted) value; reduction over 16-lane rows.
template <int CTRL>
DEV float dppadd(float v) {
    int x = __builtin_amdgcn_update_dpp(
        0, __builtin_bit_cast(int, v), CTRL, 0xF, 0xF, true);
    return v + __builtin_bit_cast(float, x);
}

// ---------------------------------------------------------------------------
// Generic C = A @ W^T + bias GEMM (unchanged from R3).
// ---------------------------------------------------------------------------
template <int ACT, typename TA, typename TW, typename OutT>
__global__ __launch_bounds__(256) void gemm_bt(
    const TA* __restrict__ A, int lda,
    const TW* __restrict__ W, int ldw,
    const float* __restrict__ bias,
    OutT* __restrict__ C, int ldc, int K)
{
    __shared__ __align__(16) unsigned short AsU[128 * 64];
    __shared__ __align__(16) unsigned short BsU[128 * 64];

    const int t     = threadIdx.x;
    const int mBase = blockIdx.y * 128;
    const int nBase = blockIdx.x * 128;
    const int wave  = t >> 6;
    const int lane  = t & 63;
    const int wm    = (wave >> 1) * 64;
    const int wn    = (wave & 1) * 64;
    const int ln15  = lane & 15;
    const int quad  = lane >> 4;

    f32x4 acc[4][4];
    const f32x4 vzero = {0.f, 0.f, 0.f, 0.f};
#pragma unroll
    for (int i = 0; i < 4; ++i)
#pragma unroll
        for (int j = 0; j < 4; ++j) acc[i][j] = vzero;

    for (int k0 = 0; k0 < K; k0 += 64) {
        bf16x8 va[4], vb[4];
#pragma unroll
        for (int i = 0; i < 4; ++i) {
            int idx = i * 256 + t;
            int r = idx >> 3;
            int c = (idx & 7) << 3;
            va[i] = ld8(A + (size_t)(mBase + r) * lda + k0 + c);
            vb[i] = ld8(W + (size_t)(nBase + r) * ldw + k0 + c);
        }
        __syncthreads();
#pragma unroll
        for (int i = 0; i < 4; ++i) {
            int idx = i * 256 + t;
            *reinterpret_cast<bf16x8*>(&AsU[idx * 8]) = va[i];
            *reinterpret_cast<bf16x8*>(&BsU[idx * 8]) = vb[i];
        }
        __syncthreads();

#pragma unroll
        for (int kk = 0; kk < 64; kk += 32) {
            const int kof = kk + quad * 8;
            bf16x8 af[4], bfr[4];
#pragma unroll
            for (int i = 0; i < 4; ++i) {
                af[i]  = *reinterpret_cast<const bf16x8*>(&AsU[(wm + i * 16 + ln15) * 64 + kof]);
                bfr[i] = *reinterpret_cast<const bf16x8*>(&BsU[(wn + i * 16 + ln15) * 64 + kof]);
            }
#pragma unroll
            for (int i = 0; i < 4; ++i)
#pragma unroll
                for (int j = 0; j < 4; ++j)
                    acc[i][j] = __builtin_amdgcn_mfma_f32_16x16x32_bf16(af[i], bfr[j], acc[i][j], 0, 0, 0);
        }
    }

#pragma unroll
    for (int i = 0; i < 4; ++i) {
        const int gm = mBase + wm + i * 16 + quad * 4;
#pragma unroll
        for (int j = 0; j < 4; ++j) {
            const int gn = nBase + wn + j * 16 + ln15;
            const float bv = bias ? bias[gn] : 0.f;
#pragma unroll
            for (int r = 0; r < 4; ++r) {
                float v = acc[i][j][r] + bv;
                if (ACT == 1) v = softplusf(v);
                storeOut(C, (size_t)(gm + r) * ldc + gn, v);
            }
        }
    }
}

// ---------------------------------------------------------------------------
// fp32 -> bf16 cast, 8 elems/thread.  n must be a multiple of 2048.
// ---------------------------------------------------------------------------
__global__ __launch_bounds__(256) void cast_f32_bf16(
    const float* __restrict__ in, __hip_bfloat16* __restrict__ out)
{
    size_t i = ((size_t)blockIdx.x * 256 + threadIdx.x) * 8;
    const float4 a = *reinterpret_cast<const float4*>(in + i);
    const float4 b = *reinterpret_cast<const float4*>(in + i + 4);
    unsigned short r[8];
    r[0] = f2bfu(a.x); r[1] = f2bfu(a.y); r[2] = f2bfu(a.z); r[3] = f2bfu(a.w);
    r[4] = f2bfu(b.x); r[5] = f2bfu(b.y); r[6] = f2bfu(b.z); r[7] = f2bfu(b.w);
    *reinterpret_cast<uint4*>(out + i) = *reinterpret_cast<uint4*>(r);
}

// ---------------------------------------------------------------------------
// wcat bf16 [256,4096]: rows 0..127 w_xdt, 128..143 w_xb, 144..159 w_xc.
// ---------------------------------------------------------------------------
__global__ __launch_bounds__(256) void build_wcat(
    const float* __restrict__ w_xdt,
    const float* __restrict__ w_xb,
    const float* __restrict__ w_xc,
    __hip_bfloat16* __restrict__ wcat)
{
    int tid = blockIdx.x * 256 + threadIdx.x;
    int r = tid >> 12;
    int c = tid & 4095;
    float v = 0.f;
    if (r < 128)      v = w_xdt[r * 4096 + c];
    else if (r < 144) v = w_xb[(r - 128) * 4096 + c];
    else if (r < 160) v = w_xc[(r - 144) * 4096 + c];
    wcat[tid] = f2bf(v);
}

// ---------------------------------------------------------------------------
// causal depthwise conv (win 4, left pad 3) + bias + silu over xz[:, :4096]
// ---------------------------------------------------------------------------
__global__ __launch_bounds__(256) void conv_silu(
    const __hip_bfloat16* __restrict__ xz,
    const float* __restrict__ conv_w,
    const float* __restrict__ conv_b,
    __hip_bfloat16* __restrict__ xc)
{
    int tid = blockIdx.x * 256 + threadIdx.x;
    int d   = tid & 4095;
    int row = tid >> 12;
    int l   = row & 1023;
    float acc = conv_b[d];
#pragma unroll
    for (int k = 0; k < 4; ++k) {
        int ll = l - 3 + k;
        if (ll >= 0)
            acc += bf2f(xz[(size_t)(row - 3 + k) * 8192 + d]) * conv_w[d * 4 + k];
    }
    xc[tid] = f2bf(siluf(acc));
}

// ---------------------------------------------------------------------------
// selective scan (R4): transposed LDS ([chan][l], padded), DPP 16-lane
// reduction (VALU pipe, not DS), register prefetch of the next time-chunk.
// 16 lanes per channel (lane=n), 16 channels/block, T=128 chunking.
// ---------------------------------------------------------------------------
#define SCAN_T 128
#define ST4 132   // fp32 row stride (16B-aligned rows, conflict-spread)
#define ST2 136   // bf16 row stride (16B-aligned rows, conflict-spread)

__global__ __launch_bounds__(256) void scan_kernel(
    const float* __restrict__ dt,              // [2048, 4096] fp32
    __hip_bfloat16* xcyg,                      // [2048, 4096] bf16 in/out
    const __hip_bfloat16* __restrict__ proj,   // [2048, 256]; B at 128, C at 144
    const __hip_bfloat16* __restrict__ xz,     // [2048, 8192]; z at 4096+d
    const float* __restrict__ A_log,           // [4096, 16] fp32
    const float* __restrict__ Dp)              // [4096] fp32
{
    __shared__ __align__(16) float          s_dt[16 * ST4];  // 8.25 KB
    __shared__ __align__(16) unsigned short s_x [16 * ST2];  // 4.25 KB
    __shared__ __align__(16) unsigned short s_z [16 * ST2];
    __shared__ __align__(16) unsigned short s_B [16 * ST2];
    __shared__ __align__(16) unsigned short s_C [16 * ST2];
    __shared__ __align__(16) unsigned short s_y [16 * ST2];

    const int t   = threadIdx.x;
    const int g   = t >> 4;                    // channel within block 0..15
    const int n   = t & 15;                    // state index
    const int ch0 = blockIdx.x * 16;
    const int b   = ch0 >> 12;
    const int d0  = ch0 & 4095;
    const int d   = d0 + g;

    const float A2   = -__expf(A_log[d * 16 + n]) * 1.44269504f; // A*log2e
    const float Dpar = Dp[d];
    const size_t rowBase = (size_t)b * 1024;

    // load-phase mappings
    const int lrow = t >> 1;                   // 0..127
    const int lh8  = (t & 1) << 3;             // 0 or 8
    const int dr0  = t >> 2,         dc0 = (t & 3) << 2;          // dt part 0
    const int dr1  = (256 + t) >> 2, dc1 = ((256 + t) & 3) << 2;  // dt part 1

    float4 rdt0, rdt1; uint4 rx, rz, rB, rC;
    auto load_chunk = [&](int t0) {
        rdt0 = *reinterpret_cast<const float4*>(&dt[(rowBase + t0 + dr0) * 4096 + d0 + dc0]);
        rdt1 = *reinterpret_cast<const float4*>(&dt[(rowBase + t0 + dr1) * 4096 + d0 + dc1]);
        rx = *reinterpret_cast<const uint4*>(&xcyg[(rowBase + t0 + lrow) * 4096 + d0 + lh8]);
        rz = *reinterpret_cast<const uint4*>(&xz[(rowBase + t0 + lrow) * 8192 + 4096 + d0 + lh8]);
        rB = *reinterpret_cast<const uint4*>(&proj[(rowBase + t0 + lrow) * 256 + 128 + lh8]);
        rC = *reinterpret_cast<const uint4*>(&proj[(rowBase + t0 + lrow) * 256 + 144 + lh8]);
    };

    load_chunk(0);
    float h = 0.f;

    for (int c = 0; c < 1024 / SCAN_T; ++c) {
        const int t0 = c * SCAN_T;
        __syncthreads();   // prev chunk LDS fully consumed
        // scatter regs -> transposed LDS
        {
            const float* pd0 = (const float*)&rdt0;
            const float* pd1 = (const float*)&rdt1;
#pragma unroll
            for (int j = 0; j < 4; ++j) {
                s_dt[(dc0 + j) * ST4 + dr0] = pd0[j];
                s_dt[(dc1 + j) * ST4 + dr1] = pd1[j];
            }
            const unsigned short* px = (const unsigned short*)&rx;
            const unsigned short* pz = (const unsigned short*)&rz;
            const unsigned short* pB = (const unsigned short*)&rB;
            const unsigned short* pC = (const unsigned short*)&rC;
#pragma unroll
            for (int j = 0; j < 8; ++j) {
                s_x[(lh8 + j) * ST2 + lrow] = px[j];
                s_z[(lh8 + j) * ST2 + lrow] = pz[j];
                s_B[(lh8 + j) * ST2 + lrow] = pB[j];
                s_C[(lh8 + j) * ST2 + lrow] = pC[j];
            }
        }
        __syncthreads();
        if (c + 1 < 1024 / SCAN_T) load_chunk(t0 + SCAN_T);

        // compute: 8-step register batches, all operands via ds_read_b128
#pragma unroll 1
        for (int l0 = 0; l0 < SCAN_T; l0 += 8) {
            const uint4 vx = *reinterpret_cast<const uint4*>(&s_x[g * ST2 + l0]);
            const uint4 vz = *reinterpret_cast<const uint4*>(&s_z[g * ST2 + l0]);
            const uint4 vB = *reinterpret_cast<const uint4*>(&s_B[n * ST2 + l0]);
            const uint4 vC = *reinterpret_cast<const uint4*>(&s_C[n * ST2 + l0]);
            const float4 vd0 = *reinterpret_cast<const float4*>(&s_dt[g * ST4 + l0]);
            const float4 vd1 = *reinterpret_cast<const float4*>(&s_dt[g * ST4 + l0 + 4]);
            const unsigned short* ux = (const unsigned short*)&vx;
            const unsigned short* uz = (const unsigned short*)&vz;
            const unsigned short* uB = (const unsigned short*)&vB;
            const unsigned short* uC = (const unsigned short*)&vC;
            const float* fd0 = (const float*)&vd0;
            const float* fd1 = (const float*)&vd1;
            unsigned short y8[8];
#pragma unroll
            for (int j = 0; j < 8; ++j) {
                const float dtv = (j < 4) ? fd0[j] : fd1[j - 4];
                const float xv  = bfu2f(ux[j]);
                const float Bn  = bfu2f(uB[j]);
                const float Cn  = bfu2f(uC[j]);
                const float e   = __builtin_amdgcn_exp2f(dtv * A2);
                h = fmaf(h, e, (xv * dtv) * Bn);
                float p = h * Cn;
                p = dppadd<0xB1>(p);    // xor 1 (quad_perm)
                p = dppadd<0x4E>(p);    // xor 2 (quad_perm)
                p = dppadd<0x141>(p);   // row_half_mirror (combine quads)
                p = dppadd<0x140>(p);   // row_mirror (combine halves)
                if (n == 0) {
                    const float zv  = bfu2f(uz[j]);
                    const float sig = __builtin_amdgcn_rcpf(
                        1.f + __builtin_amdgcn_exp2f(-zv * 1.44269504f));
                    y8[j] = f2bfu((p + Dpar * xv) * (zv * sig));
                }
            }
            if (n == 0)
                *reinterpret_cast<uint4*>(&s_y[g * ST2 + l0]) =
                    *reinterpret_cast<const uint4*>(y8);
        }
        __syncthreads();

        // y: LDS -> global (coalesced uint4)
        {
            unsigned short tmp[8];
#pragma unroll
            for (int j = 0; j < 8; ++j) tmp[j] = s_y[(lh8 + j) * ST2 + lrow];
            *reinterpret_cast<uint4*>(&xcyg[(rowBase + t0 + lrow) * 4096 + d0 + lh8]) =
                *reinterpret_cast<const uint4*>(tmp);
        }
    }
}

// ---------------------------------------------------------------------------
extern "C" void kernel_launch(void* const* d_in, const int* in_sizes, int n_in,
                              void* d_out, int out_size, void* d_ws, size_t ws_size,
                              hipStream_t stream)
{
    const float* u      = (const float*)d_in[0];
    const float* w_in   = (const float*)d_in[1];
    const float* b_in   = (const float*)d_in[2];
    const float* w_out  = (const float*)d_in[3];
    const float* b_out  = (const float*)d_in[4];
    const float* w_dt   = (const float*)d_in[5];
    const float* b_dt   = (const float*)d_in[6];
    const float* w_xdt  = (const float*)d_in[7];
    const float* w_xb   = (const float*)d_in[8];
    const float* w_xc   = (const float*)d_in[9];
    const float* conv_w = (const float*)d_in[10];
    const float* conv_b = (const float*)d_in[11];
    const float* A_log  = (const float*)d_in[12];
    const float* D_par  = (const float*)d_in[13];
    float* out = (float*)d_out;

    char* ws = (char*)d_ws;
    __hip_bfloat16* xz    = (__hip_bfloat16*)(ws);             // [2048,8192] 33.5 MB
    __hip_bfloat16* xc    = (__hip_bfloat16*)(ws + 33554432);  // [2048,4096] 16.8 MB
    __hip_bfloat16* u_bf  = (__hip_bfloat16*)(ws + 33554432);  // [2048,2048] 8.4 MB (dead before xc written)
    __hip_bfloat16* wcat  = (__hip_bfloat16*)(ws + 50331648);  // [256,4096]  2.1 MB
    __hip_bfloat16* proj  = (__hip_bfloat16*)(ws + 52428800);  // [2048,256]  1.0 MB
    float*          dtb   = (float*)(ws + 53477376);           // [2048,4096] 33.5 MB
    __hip_bfloat16* w_in_bf  = (__hip_bfloat16*)(ws + 53477376); // dead before dtb written
    __hip_bfloat16* w_out_bf = (__hip_bfloat16*)(ws + 53477376); // written after scan (dtb dead)
    // total 87.0 MB

    // 0. pre-cast activations/weights to bf16
    cast_f32_bf16<<<2048, 256, 0, stream>>>(u, u_bf);        // 4.19M elems
    cast_f32_bf16<<<8192, 256, 0, stream>>>(w_in, w_in_bf);  // 16.78M elems

    // 1. weight concat
    build_wcat<<<4096, 256, 0, stream>>>(w_xdt, w_xb, w_xc, wcat);

    // 2. in_proj: xz = u @ w_in^T + b_in     (M=2048, N=8192, K=2048)
    gemm_bt<0, __hip_bfloat16, __hip_bfloat16, __hip_bfloat16><<<dim3(64, 16), 256, 0, stream>>>(
        u_bf, 2048, w_in_bf, 2048, b_in, xz, 8192, 2048);

    // 3. conv + silu (overwrites u_bf region with xc)
    conv_silu<<<32768, 256, 0, stream>>>(xz, conv_w, conv_b, xc);

    // 4. proj = xc @ wcat^T                  (M=2048, N=256, K=4096)
    gemm_bt<0, __hip_bfloat16, __hip_bfloat16, __hip_bfloat16><<<dim3(2, 16), 256, 0, stream>>>(
        xc, 4096, wcat, 4096, (const float*)nullptr, proj, 256, 4096);

    // 5. dt = softplus(proj[:, :128] @ w_dt^T + b_dt)  (M=2048, N=4096, K=128)
    gemm_bt<1, __hip_bfloat16, float, float><<<dim3(32, 16), 256, 0, stream>>>(
        proj, 256, w_dt, 128, b_dt, dtb, 4096, 128);

    // 6. selective scan -> yg (in-place over xc)
    scan_kernel<<<512, 256, 0, stream>>>(dtb, xc, proj, xz, A_log, D_par);

    // 7. cast w_out (dtb region is dead now)
    cast_f32_bf16<<<4096, 256, 0, stream>>>(w_out, w_out_bf); // 8.39M elems

    // 8. out = yg @ w_out^T + b_out          (M=2048, N=2048, K=4096)
    gemm_bt<0, __hip_bfloat16, __hip_bfloat16, float><<<dim3(16, 16), 256, 0, stream>>>(
        xc, 4096, w_out_bf, 4096, b_out, out, 2048, 4096);
}